// Round 14
// baseline (98.434 us; speedup 1.0000x reference)
//
#include <hip/hip_runtime.h>

#define B_ROWS 8192
#define IN_DIM 512
#define OUT_DIM 512
#define NDEG 8                 // DEGREE+1
#define KDIM (IN_DIM * NDEG)   // 4096
#define ZSLICES 4
#define NKT 16                 // K-tiles (of 64) per z-slice

typedef short bf16x8 __attribute__((ext_vector_type(8)));
typedef float f32x4  __attribute__((ext_vector_type(4)));

#define SB __builtin_amdgcn_sched_barrier(0)

__device__ __forceinline__ unsigned short f2bf(float f) {
  unsigned u = __float_as_uint(f);
  u += 0x7fffu + ((u >> 16) & 1u);   // RNE
  return (unsigned short)(u >> 16);
}

__device__ __forceinline__ void laguerre8(float t, float* L) {
  L[0] = 1.0f;
  L[1] = 1.5f - t;
#pragma unroll
  for (int k = 2; k < NDEG; ++k)
    L[k] = ((2.0f * (float)k - 0.5f - t) * L[k - 1] -
            ((float)k - 0.5f) * L[k - 2]) * (1.0f / (float)k);
}

__device__ __forceinline__ float ftanh(float x) {
  float e2 = __expf(2.0f * x);
  return (e2 - 1.0f) * (1.0f / (e2 + 1.0f));
}

// A-fragment from ONE x value: 8 contiguous k of a fragment = the 8 degrees.
// round-half-away (u+0x8000) — 1 op/value vs RNE's 4; error still <= 0.5 ULP.
__device__ __forceinline__ bf16x8 bpack8(float xv) {
  float L[NDEG];
  laguerre8(ftanh(xv), L);
  bf16x8 r;
#pragma unroll
  for (int d = 0; d < NDEG; ++d)
    r[d] = (short)((__float_as_uint(L[d]) + 0x8000u) >> 16);
  return r;
}

// Bt brick layout (verified r5-r13; SQ_LDS_BANK_CONFLICT==0):
// chunk = (rowblk*64 + ktile)*1024 + (rb>>6)*512 + (rb&63)*8 + (c ^ (rb&7))

// ---- pass 1: coeffs -> Bt bricks only (A is never materialized) -----------------
__global__ void prep_kernel(const float* __restrict__ cf, unsigned short* __restrict__ Bt) {
  int idx = blockIdx.x * 256 + threadIdx.x;   // i*512 + o
  int i = idx >> 9, o = idx & 511;
  const float4* cp = (const float4*)(cf + (size_t)idx * 8);
  float4 c0 = cp[0], c1 = cp[1];
  uint4 v;
  v.x = (unsigned)f2bf(c0.x) | ((unsigned)f2bf(c0.y) << 16);
  v.y = (unsigned)f2bf(c0.z) | ((unsigned)f2bf(c0.w) << 16);
  v.z = (unsigned)f2bf(c1.x) | ((unsigned)f2bf(c1.y) << 16);
  v.w = (unsigned)f2bf(c1.z) | ((unsigned)f2bf(c1.w) << 16);
  int h = o >> 7, rb = o & 127, t = i >> 3, c = i & 7;
  size_t chunk = ((size_t)(h * 64 + t)) * 1024 + (rb >> 6) * 512 + (rb & 63) * 8 + (c ^ (rb & 7));
  ((uint4*)Bt)[chunk] = v;
}

// ---- pass 2: GEMM 256x256, A-in-registers (x -> bpack -> fragment) --------------
// B double-buffered in LDS (32 KB/tile), 2 barriers/tile, counted vmcnt.
// A: per fragment, 1 x float + bpack8 — pure VALU, no LDS, no sync; overlaps MFMA.

#define LDB_(SET, cur, ks)                                                         \
  { const unsigned short* Bb_ = lds + (cur) * 16384 + (wn >> 1) * 8192             \
                                + (wn & 1) * 4096 + arow * 64;                     \
    _Pragma("unroll") for (int ni = 0; ni < 4; ++ni)                               \
      SET[ni] = *(const bf16x8*)(Bb_ + ni * 1024 + (e ^ ((ks) * 32))); }

#define XL(dst, tt, mq, ks)                                                        \
  { _Pragma("unroll") for (int m4 = 0; m4 < 4; ++m4)                               \
      dst[m4] = xb[((mq) * 64 + m4 * 16) * 512 + (tt) * 8 + (ks) * 4]; }

#define BP(dst, src)                                                               \
  { _Pragma("unroll") for (int m4 = 0; m4 < 4; ++m4) dst[m4] = bpack8(src[m4]); }

#define MM(ASET, BSET, mq)                                                         \
  { __builtin_amdgcn_s_setprio(1);                                                 \
    _Pragma("unroll") for (int m4 = 0; m4 < 4; ++m4)                               \
      _Pragma("unroll") for (int ni = 0; ni < 4; ++ni)                             \
        acc[(mq) * 4 + m4][ni] = __builtin_amdgcn_mfma_f32_16x16x32_bf16(          \
            ASET[m4], BSET[ni], acc[(mq) * 4 + m4][ni], 0, 0, 0);                  \
    __builtin_amdgcn_s_setprio(0); }

// one tile: 4 phases (mq,ks); x loads for each phase issued one phase early
#define COMPUTE(cur, tt)                                                           \
  { LDB_(bfA, cur, 0); XL(xq, tt, 1, 0);                                           \
    BP(af, xp); MM(af, bfA, 0);                                                    \
    XL(xr, tt, 0, 1);                                                              \
    BP(af, xq); MM(af, bfA, 1);                                                    \
    LDB_(bfB, cur, 1); XL(xq, tt, 1, 1);                                           \
    BP(af, xr); MM(af, bfB, 0);                                                    \
    BP(af, xq); MM(af, bfB, 1); }

__global__ __launch_bounds__(512, 2) void gemm_kernel(const float* __restrict__ x,
                                                      const unsigned short* __restrict__ Bt,
                                                      unsigned short* __restrict__ P) {
  __shared__ unsigned short lds[65536];   // 128 KB: B ring 2x32KB at offset 0; epilogue uses all

  const int tid = threadIdx.x;
  const int lane = tid & 63;
  const int w = tid >> 6;
  const int wm = w >> 2, wn = w & 3;

  // bijective decode, x-panel sharers co-XCD
  const int g = blockIdx.x;               // 0..255
  const int j0 = g >> 3, xx = g & 7;
  const int My = ((j0 >> 3) << 3) | xx;   // 0..31
  const int n = (j0 >> 2) & 1;            // 0..1
  const int z = j0 & 3;                   // 0..3

  const uint4* Bg = (const uint4*)Bt;

  const int arow = lane & 15, hi = lane >> 4;
  const int e = (hi ^ (arow & 7)) * 8;    // swizzled chunk offset (shorts)

  // this thread's A-fragment x base: row = My*256 + wm*128 + mq*64 + m4*16 + arow
  //                                  i   = z*128 + t*8 + ks*4 + hi
  const float* xb = x + ((size_t)(My * 256 + wm * 128 + arow)) * 512 + z * 128 + hi;

  f32x4 zero = {0.f, 0.f, 0.f, 0.f};
  f32x4 acc[8][4];
#pragma unroll
  for (int mi = 0; mi < 8; ++mi)
#pragma unroll
    for (int ni = 0; ni < 4; ++ni) acc[mi][ni] = zero;

  // stage one B tile (2 half-bricks, 32 KB): 4 gl_lds per wave
  auto STAGE = [&](int tile, int buf) {
#pragma unroll
    for (int h = 0; h < 2; ++h) {
      const size_t c0 = ((size_t)((n * 2 + h) * 64 + z * NKT + tile)) * 1024 + w * 64 + lane;
      unsigned short* d = lds + buf * 16384 + h * 8192 + w * 512;
      __builtin_amdgcn_global_load_lds(
          (const __attribute__((address_space(1))) unsigned int*)(Bg + c0),
          (__attribute__((address_space(3))) unsigned int*)d, 16, 0, 0);
      __builtin_amdgcn_global_load_lds(
          (const __attribute__((address_space(1))) unsigned int*)(Bg + c0 + 512),
          (__attribute__((address_space(3))) unsigned int*)(d + 4096), 16, 0, 0);
    }
  };

  bf16x8 af[4], bfA[4], bfB[4];
  float xp[4], xq[4], xr[4];

  // ---- prologue: B(0)->buf0, B(1)->buf1; x for (t0,p0) ----
  STAGE(0, 0); STAGE(1, 1);
  XL(xp, 0, 0, 0);
  asm volatile("s_waitcnt vmcnt(8)" ::: "memory");   // B(0) landed; B(1)+xp in flight
  SB;
  __builtin_amdgcn_s_barrier(); SB;

  // ---- main loop: t = 0..13 ----
#pragma unroll 2
  for (int t = 0; t < NKT - 2; ++t) {
    const int cur = t & 1;
    COMPUTE(cur, t);
    XL(xp, t + 1, 0, 0);                             // prefetch next tile p0
    __builtin_amdgcn_s_barrier(); SB;                // all waves done reading buf[cur]
    STAGE(t + 2, cur);
    asm volatile("s_waitcnt vmcnt(8)" ::: "memory"); // B(t+1) landed (xp+B(t+2) out)
    SB;
    __builtin_amdgcn_s_barrier(); SB;                // publish B(t+1)
  }
  // ---- peel t=14: publish B(15); t=15: compute, no staging ----
  COMPUTE(0, 14);
  XL(xp, 15, 0, 0);
  asm volatile("s_waitcnt vmcnt(4)" ::: "memory");   // B(15) landed (xp out)
  SB;
  __builtin_amdgcn_s_barrier(); SB;
  COMPUTE(1, 15);
  __syncthreads();                                   // reads done before LDS reuse

  // ---- epilogue: bf16 via per-wave LDS bounce (swizzled) -> uint4 line stores ----
  unsigned short* W = lds + w * 8192;    // 128 rows x 64 shorts per wave
#pragma unroll
  for (int mi = 0; mi < 8; ++mi)
#pragma unroll
    for (int ni = 0; ni < 4; ++ni) {
      int col = ni * 16 + arow;
      int c8 = col >> 3, cpos = col & 7;
#pragma unroll
      for (int r = 0; r < 4; ++r) {
        int row = mi * 16 + hi * 4 + r;
        W[row * 64 + ((c8 ^ (row & 7)) << 3) + cpos] = f2bf(acc[mi][ni][r]);
      }
    }
  const int rr = lane >> 3, cc = lane & 7;
#pragma unroll
  for (int it = 0; it < 16; ++it) {
    int row = it * 8 + rr;
    uint4 v = *(uint4*)&W[row * 64 + ((cc ^ (row & 7)) << 3)];
    size_t pr = ((size_t)z * B_ROWS + My * 256 + wm * 128 + row) * 512 + n * 256 + wn * 64 + cc * 8;
    *(uint4*)&P[pr] = v;
  }
}

// ---- pass 3: out = sum of bf16 partials, f32 (r6 verbatim) ----------------------
__global__ void reduce_kernel(const unsigned short* __restrict__ P, float* __restrict__ out) {
  size_t t = (size_t)blockIdx.x * 256 + threadIdx.x;
  const uint4* p = (const uint4*)P;
  const size_t stride = (size_t)B_ROWS * OUT_DIM / 8;
  float s[8] = {0, 0, 0, 0, 0, 0, 0, 0};
#pragma unroll
  for (int zz = 0; zz < ZSLICES; ++zz) {
    uint4 v = p[t + zz * stride];
    unsigned q[4] = {v.x, v.y, v.z, v.w};
#pragma unroll
    for (int j = 0; j < 4; ++j) {
      s[2 * j]     += __uint_as_float((q[j] & 0xffffu) << 16);
      s[2 * j + 1] += __uint_as_float(q[j] & 0xffff0000u);
    }
  }
  float4 o0 = {s[0], s[1], s[2], s[3]}, o1 = {s[4], s[5], s[6], s[7]};
  ((float4*)out)[t * 2]     = o0;
  ((float4*)out)[t * 2 + 1] = o1;
}

// ---- fallback -------------------------------------------------------------------
__global__ void naive_kernel(const float* __restrict__ x, const float* __restrict__ c,
                             float* __restrict__ out) {
  __shared__ float bas[IN_DIM * NDEG];
  int b = blockIdx.x;
  for (int i = threadIdx.x; i < IN_DIM; i += 256) {
    float L[NDEG];
    laguerre8(tanhf(x[(size_t)b * IN_DIM + i]), L);
#pragma unroll
    for (int d = 0; d < NDEG; ++d) bas[i * NDEG + d] = L[d];
  }
  __syncthreads();
  for (int o = threadIdx.x; o < OUT_DIM; o += 256) {
    float acc = 0.f;
    for (int i = 0; i < IN_DIM; ++i) {
      const float* cp = c + ((size_t)i * OUT_DIM + o) * NDEG;
#pragma unroll
      for (int d = 0; d < NDEG; ++d) acc += bas[i * NDEG + d] * cp[d];
    }
    out[(size_t)b * OUT_DIM + o] = acc;
  }
}

extern "C" void kernel_launch(void* const* d_in, const int* in_sizes, int n_in,
                              void* d_out, int out_size, void* d_ws, size_t ws_size,
                              hipStream_t stream) {
  const float* x    = (const float*)d_in[0];
  const float* coef = (const float*)d_in[1];
  float* out = (float*)d_out;

  const size_t P_B  = (size_t)ZSLICES * B_ROWS * OUT_DIM * 2; // 32 MiB
  const size_t BT_B = (size_t)OUT_DIM * KDIM * 2;             // 4 MiB

  if (ws_size >= P_B + BT_B) {   // 36 MiB (>=100 MiB proven earlier)
    unsigned short* Pp = (unsigned short*)d_ws;
    unsigned short* Bt = (unsigned short*)((char*)d_ws + P_B);
    prep_kernel<<<(IN_DIM * OUT_DIM) / 256, 256, 0, stream>>>(coef, Bt);
    gemm_kernel<<<256, 512, 0, stream>>>(x, Bt, Pp);
    reduce_kernel<<<(B_ROWS * OUT_DIM / 8) / 256, 256, 0, stream>>>(Pp, out);
  } else {
    naive_kernel<<<B_ROWS, 256, 0, stream>>>(x, coef, out);
  }
}

// Round 15
// 66.775 us; speedup vs baseline: 1.4741x; 1.4741x over previous
//
#include <hip/hip_runtime.h>

#define B_ROWS 8192
#define IN_DIM 512
#define OUT_DIM 512
#define NDEG 8                 // DEGREE+1
#define KDIM (IN_DIM * NDEG)   // 4096
#define ZS 2                   // K-split slices
#define NKT 32                 // K-tiles (of 64) per z-slice

typedef short bf16x8 __attribute__((ext_vector_type(8)));
typedef float f32x4  __attribute__((ext_vector_type(4)));

#define SB __builtin_amdgcn_sched_barrier(0)

__device__ __forceinline__ unsigned short f2bf(float f) {
  unsigned u = __float_as_uint(f);
  u += 0x7fffu + ((u >> 16) & 1u);   // RNE
  return (unsigned short)(u >> 16);
}

__device__ __forceinline__ void laguerre8(float t, float* L) {
  L[0] = 1.0f;
  L[1] = 1.5f - t;
#pragma unroll
  for (int k = 2; k < NDEG; ++k)
    L[k] = ((2.0f * (float)k - 0.5f - t) * L[k - 1] -
            ((float)k - 0.5f) * L[k - 2]) * (1.0f / (float)k);
}

__device__ __forceinline__ float ftanh(float x) {
  float e2 = __expf(2.0f * x);
  return (e2 - 1.0f) * (1.0f / (e2 + 1.0f));
}

__device__ __forceinline__ uint4 bpack(float xv) {
  float L[NDEG];
  laguerre8(ftanh(xv), L);
  uint4 v;
  v.x = (unsigned)f2bf(L[0]) | ((unsigned)f2bf(L[1]) << 16);
  v.y = (unsigned)f2bf(L[2]) | ((unsigned)f2bf(L[3]) << 16);
  v.z = (unsigned)f2bf(L[4]) | ((unsigned)f2bf(L[5]) << 16);
  v.w = (unsigned)f2bf(L[6]) | ((unsigned)f2bf(L[7]) << 16);
  return v;
}

// Brick layout (A and B identical; SQ_LDS_BANK_CONFLICT==0 verified r5-r13):
// 128-row x 64-k bricks of 16B chunks:
//   chunk = (rowblk*64 + ktile)*1024 + (rb>>6)*512 + (rb&63)*8 + (c ^ (rb&7))

// ---- pass 1: basis -> A bricks | coeffs -> Bt bricks (r6 version, unchanged) ----
__global__ void prep_kernel(const float* __restrict__ x, const float* __restrict__ cf,
                            unsigned short* __restrict__ A, unsigned short* __restrict__ Bt) {
  int g = blockIdx.x;
  if (g < (B_ROWS * IN_DIM) / 256) {
    int idx = g * 256 + threadIdx.x;
    int b = idx >> 9, i = idx & 511;     // k = i*8 + d
    uint4 v = bpack(x[idx]);
    int h = b >> 7, rb = b & 127, t = i >> 3, c = i & 7;
    size_t chunk = ((size_t)(h * 64 + t)) * 1024 + (rb >> 6) * 512 + (rb & 63) * 8 + (c ^ (rb & 7));
    ((uint4*)A)[chunk] = v;
  } else {
    int idx = (g - (B_ROWS * IN_DIM) / 256) * 256 + threadIdx.x;   // i*512 + o
    int i = idx >> 9, o = idx & 511;
    const float4* cp = (const float4*)(cf + (size_t)idx * 8);
    float4 c0 = cp[0], c1 = cp[1];
    uint4 v;
    v.x = (unsigned)f2bf(c0.x) | ((unsigned)f2bf(c0.y) << 16);
    v.y = (unsigned)f2bf(c0.z) | ((unsigned)f2bf(c0.w) << 16);
    v.z = (unsigned)f2bf(c1.x) | ((unsigned)f2bf(c1.y) << 16);
    v.w = (unsigned)f2bf(c1.z) | ((unsigned)f2bf(c1.w) << 16);
    int h = o >> 7, rb = o & 127, t = i >> 3, c = i & 7;
    size_t chunk = ((size_t)(h * 64 + t)) * 1024 + (rb >> 6) * 512 + (rb & 63) * 8 + (c ^ (rb & 7));
    ((uint4*)Bt)[chunk] = v;
  }
}

// ---- pass 2: GEMM 128x128, 4 waves, 2 blocks/CU, counted-vmcnt double buffer ----
// Cross-block TLP provides MFMA||LDS overlap that barrier-locked schedules could
// not (r5/r6/r12/r13 all ~36-41 us). No setprio (starves the co-block's reads).
__global__ __launch_bounds__(256, 2) void gemm_kernel(const unsigned short* __restrict__ A,
                                                      const unsigned short* __restrict__ Bt,
                                                      unsigned short* __restrict__ P) {
  __shared__ unsigned short lds[32768];   // 64 KB: A0|A1 (8192 shorts each), B0|B1

  const int tid = threadIdx.x;
  const int lane = tid & 63;
  const int w = tid >> 6;                 // 0..3
  const int wm = w >> 1, wn = w & 1;      // 2m x 2n, wave-tile 64x64

  // bijective decode; same-My blocks (all n,z) co-XCD for A-panel L2 reuse
  const int g = blockIdx.x;               // 0..511
  const int xx = g & 7, hy = (g >> 3) & 7;
  const int My = hy * 8 + xx;             // 0..63
  const int n = (g >> 6) & 3;             // 0..3
  const int z = (g >> 8) & 1;             // 0..1

  const uint4* Ag = (const uint4*)A;
  const uint4* Bg = (const uint4*)Bt;

  const int arow = lane & 15, hi = lane >> 4;
  const int e = (hi ^ (arow & 7)) * 8;    // swizzled chunk offset (shorts)

  f32x4 zero = {0.f, 0.f, 0.f, 0.f};
  f32x4 acc[4][4];
#pragma unroll
  for (int mi = 0; mi < 4; ++mi)
#pragma unroll
    for (int ni = 0; ni < 4; ++ni) acc[mi][ni] = zero;

  // stage one 32 KB tile (A 16 KB + B 16 KB): 8 gl_lds per wave
  auto STAGE = [&](int tile, int buf) {
    const int tg = z * NKT + tile;
    const size_t cA = ((size_t)(My * 64 + tg)) * 1024 + w * 256 + lane;
    const size_t cB = ((size_t)(n * 64 + tg)) * 1024 + w * 256 + lane;
    unsigned short* dA = lds + buf * 8192 + w * 2048;
    unsigned short* dB = lds + 16384 + buf * 8192 + w * 2048;
#pragma unroll
    for (int j = 0; j < 4; ++j) {
      __builtin_amdgcn_global_load_lds(
          (const __attribute__((address_space(1))) unsigned int*)(Ag + cA + j * 64),
          (__attribute__((address_space(3))) unsigned int*)(dA + j * 512), 16, 0, 0);
      __builtin_amdgcn_global_load_lds(
          (const __attribute__((address_space(1))) unsigned int*)(Bg + cB + j * 64),
          (__attribute__((address_space(3))) unsigned int*)(dB + j * 512), 16, 0, 0);
    }
  };

  auto COMPUTE = [&](int buf) {
    const unsigned short* Ab = lds + buf * 8192 + wm * 4096 + arow * 64;
    const unsigned short* Bb = lds + 16384 + buf * 8192 + wn * 4096 + arow * 64;
#pragma unroll
    for (int ks = 0; ks < 2; ++ks) {
      const int o = e ^ (ks * 32);
      bf16x8 af[4], bfr[4];
#pragma unroll
      for (int m4 = 0; m4 < 4; ++m4) af[m4] = *(const bf16x8*)(Ab + m4 * 1024 + o);
#pragma unroll
      for (int ni = 0; ni < 4; ++ni) bfr[ni] = *(const bf16x8*)(Bb + ni * 1024 + o);
#pragma unroll
      for (int m4 = 0; m4 < 4; ++m4)
#pragma unroll
        for (int ni = 0; ni < 4; ++ni)
          acc[m4][ni] = __builtin_amdgcn_mfma_f32_16x16x32_bf16(af[m4], bfr[ni], acc[m4][ni], 0, 0, 0);
    }
  };

  // ---- prologue: tiles 0,1 in flight (8 loads each) ----
  STAGE(0, 0); STAGE(1, 1);
  asm volatile("s_waitcnt vmcnt(8)" ::: "memory");   // tile0 landed; tile1 in flight
  SB;
  __builtin_amdgcn_s_barrier(); SB;

  // ---- main loop: t = 0..29 ----
  for (int t = 0; t < NKT - 2; ++t) {
    const int cur = t & 1;
    COMPUTE(cur);
    asm volatile("s_waitcnt lgkmcnt(0)" ::: "memory");   // my reads of buf[cur] done
    SB;
    __builtin_amdgcn_s_barrier(); SB;                    // all waves done reading
    STAGE(t + 2, cur);                                   // overwrite with t+2
    asm volatile("s_waitcnt vmcnt(8)" ::: "memory");     // t+1 landed (t+2 in flight)
    SB;
    __builtin_amdgcn_s_barrier(); SB;                    // publish t+1
  }
  // ---- peel t=30,31 ----
  COMPUTE(0);
  asm volatile("s_waitcnt vmcnt(0)" ::: "memory");       // tile31 landed
  SB;
  __builtin_amdgcn_s_barrier(); SB;
  COMPUTE(1);
  __syncthreads();                                       // drain before LDS reuse

  // ---- epilogue: bf16 via per-wave LDS bounce (swizzled) -> uint4 line stores ----
  unsigned short* W = lds + w * 8192;    // 64 rows x 64 shorts per wave (swizzled)
#pragma unroll
  for (int mi = 0; mi < 4; ++mi)
#pragma unroll
    for (int ni = 0; ni < 4; ++ni) {
      int col = ni * 16 + arow;
      int c8 = col >> 3, cpos = col & 7;
#pragma unroll
      for (int r = 0; r < 4; ++r) {
        int row = mi * 16 + hi * 4 + r;
        W[row * 64 + ((c8 ^ (row & 7)) << 3) + cpos] = f2bf(acc[mi][ni][r]);
      }
    }
  const int rr = lane >> 3, cc = lane & 7;
#pragma unroll
  for (int it = 0; it < 8; ++it) {
    int row = it * 8 + rr;
    uint4 v = *(uint4*)&W[row * 64 + ((cc ^ (row & 7)) << 3)];
    size_t pr = ((size_t)z * B_ROWS + My * 128 + wm * 64 + row) * 512 + n * 128 + wn * 64 + cc * 8;
    *(uint4*)&P[pr] = v;
  }
}

// ---- pass 3: out = sum of ZS bf16 partials, f32 ---------------------------------
__global__ void reduce_kernel(const unsigned short* __restrict__ P, float* __restrict__ out) {
  size_t t = (size_t)blockIdx.x * 256 + threadIdx.x;
  const uint4* p = (const uint4*)P;
  const size_t stride = (size_t)B_ROWS * OUT_DIM / 8;
  float s[8] = {0, 0, 0, 0, 0, 0, 0, 0};
#pragma unroll
  for (int zz = 0; zz < ZS; ++zz) {
    uint4 v = p[t + zz * stride];
    unsigned q[4] = {v.x, v.y, v.z, v.w};
#pragma unroll
    for (int j = 0; j < 4; ++j) {
      s[2 * j]     += __uint_as_float((q[j] & 0xffffu) << 16);
      s[2 * j + 1] += __uint_as_float(q[j] & 0xffff0000u);
    }
  }
  float4 o0 = {s[0], s[1], s[2], s[3]}, o1 = {s[4], s[5], s[6], s[7]};
  ((float4*)out)[t * 2]     = o0;
  ((float4*)out)[t * 2 + 1] = o1;
}

// ---- fallback -------------------------------------------------------------------
__global__ void naive_kernel(const float* __restrict__ x, const float* __restrict__ c,
                             float* __restrict__ out) {
  __shared__ float bas[IN_DIM * NDEG];
  int b = blockIdx.x;
  for (int i = threadIdx.x; i < IN_DIM; i += 256) {
    float L[NDEG];
    laguerre8(tanhf(x[(size_t)b * IN_DIM + i]), L);
#pragma unroll
    for (int d = 0; d < NDEG; ++d) bas[i * NDEG + d] = L[d];
  }
  __syncthreads();
  for (int o = threadIdx.x; o < OUT_DIM; o += 256) {
    float acc = 0.f;
    for (int i = 0; i < IN_DIM; ++i) {
      const float* cp = c + ((size_t)i * OUT_DIM + o) * NDEG;
#pragma unroll
      for (int d = 0; d < NDEG; ++d) acc += bas[i * NDEG + d] * cp[d];
    }
    out[(size_t)b * OUT_DIM + o] = acc;
  }
}

extern "C" void kernel_launch(void* const* d_in, const int* in_sizes, int n_in,
                              void* d_out, int out_size, void* d_ws, size_t ws_size,
                              hipStream_t stream) {
  const float* x    = (const float*)d_in[0];
  const float* coef = (const float*)d_in[1];
  float* out = (float*)d_out;

  const size_t A_B  = (size_t)B_ROWS * KDIM * 2;              // 64 MiB
  const size_t P_B  = (size_t)ZS * B_ROWS * OUT_DIM * 2;      // 16 MiB
  const size_t BT_B = (size_t)OUT_DIM * KDIM * 2;             // 4 MiB

  if (ws_size >= A_B + P_B + BT_B) {   // 84 MiB (>=100 MiB proven rounds 3-14)
    unsigned short* Abuf = (unsigned short*)d_ws;
    unsigned short* Pp   = (unsigned short*)((char*)d_ws + A_B);
    unsigned short* Bt   = (unsigned short*)((char*)d_ws + A_B + P_B);
    prep_kernel<<<(B_ROWS * IN_DIM) / 256 + (IN_DIM * OUT_DIM) / 256, 256, 0, stream>>>(x, coef, Abuf, Bt);
    gemm_kernel<<<512, 256, 0, stream>>>(Abuf, Bt, Pp);
    reduce_kernel<<<(B_ROWS * OUT_DIM / 8) / 256, 256, 0, stream>>>(Pp, out);
  } else {
    naive_kernel<<<B_ROWS, 256, 0, stream>>>(x, coef, out);
  }
}